// Round 2
// baseline (904.283 us; speedup 1.0000x reference)
//
#include <hip/hip_runtime.h>

#define D_MODEL 2048
#define NHEADS 16
#define DHEAD 128
#define TSEQ 2048
#define BATCH 4
#define MROWS (BATCH*TSEQ)   // 8192
#define NQKV (3*D_MODEL)     // 6144
#define BH (BATCH*NHEADS)    // 64

typedef __attribute__((ext_vector_type(4))) float f32x4;
typedef __attribute__((ext_vector_type(8))) __bf16 bf16x8;
typedef __attribute__((ext_vector_type(4))) unsigned int u32x4;

__device__ inline unsigned short f2bf(float f) {
  union { float f; unsigned u; } v; v.f = f;
  unsigned r = (v.u + 0x7fffu + ((v.u >> 16) & 1u)) >> 16;
  return (unsigned short)r;
}
__device__ inline float bf2f(unsigned short h) {
  union { unsigned u; float f; } v; v.u = ((unsigned)h) << 16; return v.f;
}

// ---------------- fp32 -> bf16 convert (vectorized, G13) ----------------
__global__ __launch_bounds__(256) void cvt_bf16(const float* __restrict__ in,
                                                unsigned short* __restrict__ out, int n) {
  int i = (blockIdx.x * 256 + threadIdx.x) * 8;
  if (i >= n) return;
  float4 a = *(const float4*)(in + i);
  float4 b = *(const float4*)(in + i + 4);
  union { unsigned short s[8]; u32x4 v; } r;
  r.s[0] = f2bf(a.x); r.s[1] = f2bf(a.y); r.s[2] = f2bf(a.z); r.s[3] = f2bf(a.w);
  r.s[4] = f2bf(b.x); r.s[5] = f2bf(b.y); r.s[6] = f2bf(b.z); r.s[7] = f2bf(b.w);
  *(u32x4*)(out + i) = r.v;
}

// ---------------- w [K][N] fp32 -> wT [N][K] bf16 ----------------
__global__ __launch_bounds__(256) void transw(const float* __restrict__ w,
                                              unsigned short* __restrict__ wt, int K, int N) {
  __shared__ float tile[32][33];
  int n0 = blockIdx.x * 32, k0 = blockIdx.y * 32;
  int x = threadIdx.x & 31, y = threadIdx.x >> 5;
  #pragma unroll
  for (int j = 0; j < 4; ++j)
    tile[y + j * 8][x] = w[(size_t)(k0 + y + j * 8) * N + n0 + x];
  __syncthreads();
  #pragma unroll
  for (int j = 0; j < 4; ++j)
    wt[(size_t)(n0 + y + j * 8) * K + k0 + x] = f2bf(tile[x][y + j * 8]);
}

// ---------------- RoPE cos/sin table: tab[t][f], f in [0,64) ----------------
__global__ void rope_table(float2* __restrict__ tab) {
  int t = blockIdx.x, f = threadIdx.x;
  float inv = __expf(-0.14391156831212787f * (float)f); // ln(10000)/64
  float ang = (float)t * inv;
  tab[t * 64 + f] = make_float2(cosf(ang), sinf(ang));
}

// ---------------- apply rotate-half RoPE in place on [BH][T][128] bf16 ----------------
__global__ __launch_bounds__(256) void rope_apply(unsigned short* __restrict__ X,
                                                  const float2* __restrict__ tab) {
  int row = blockIdx.x * 4 + (threadIdx.x >> 6);
  int f = threadIdx.x & 63;
  int t = row & (TSEQ - 1);
  unsigned short* p = X + (size_t)row * DHEAD;
  float2 cs = tab[t * 64 + f];
  float x1 = bf2f(p[f]), x2 = bf2f(p[f + 64]);
  p[f]      = f2bf(x1 * cs.x - x2 * cs.y);
  p[f + 64] = f2bf(x2 * cs.x + x1 * cs.y);
}

// ---------------- GEMM: C[M][N] = A[M][K] @ Bt[N][K]^T + bias ----------------
// MODE 0: scatter to Qb/Kb (head-major) and VTb (transposed V). MODE 1: fp32 out.
template<int MODE>
__global__ __launch_bounds__(256) void gemm_bt(
    const unsigned short* __restrict__ A,
    const unsigned short* __restrict__ Bt,
    const float* __restrict__ bias,
    int M, int N, int K,
    unsigned short* __restrict__ Qb,
    unsigned short* __restrict__ Kb,
    unsigned short* __restrict__ VTb,
    float* __restrict__ outF)
{
  __shared__ unsigned short Asm_[128 * 72];
  __shared__ unsigned short Bsm_[128 * 72];
  int tid = threadIdx.x;
  int wid = tid >> 6, lane = tid & 63;
  int wm = wid >> 1, wn = wid & 1;
  int l15 = lane & 15, l16 = lane >> 4;
  int row0 = blockIdx.y * 128, col0 = blockIdx.x * 128;
  f32x4 acc[4][4] = {};

  for (int k0 = 0; k0 < K; k0 += 64) {
    #pragma unroll
    for (int c = 0; c < 4; ++c) {
      int e = (c * 256 + tid) * 8;
      int r = e >> 6, cc = e & 63;
      *(u32x4*)&Asm_[r * 72 + cc] = *(const u32x4*)&A[(size_t)(row0 + r) * K + k0 + cc];
      *(u32x4*)&Bsm_[r * 72 + cc] = *(const u32x4*)&Bt[(size_t)(col0 + r) * K + k0 + cc];
    }
    __syncthreads();
    #pragma unroll
    for (int kk = 0; kk < 2; ++kk) {
      bf16x8 av[4], bv[4];
      #pragma unroll
      for (int m = 0; m < 4; ++m)
        av[m] = *(const bf16x8*)&Asm_[(wm * 64 + m * 16 + l15) * 72 + kk * 32 + l16 * 8];
      #pragma unroll
      for (int n = 0; n < 4; ++n)
        bv[n] = *(const bf16x8*)&Bsm_[(wn * 64 + n * 16 + l15) * 72 + kk * 32 + l16 * 8];
      #pragma unroll
      for (int m = 0; m < 4; ++m)
        #pragma unroll
        for (int n = 0; n < 4; ++n)
          acc[m][n] = __builtin_amdgcn_mfma_f32_16x16x32_bf16(av[m], bv[n], acc[m][n], 0, 0, 0);
    }
    __syncthreads();
  }

  #pragma unroll
  for (int m = 0; m < 4; ++m) {
    #pragma unroll
    for (int n = 0; n < 4; ++n) {
      int col = col0 + wn * 64 + n * 16 + l15;
      float bs = bias[col];
      #pragma unroll
      for (int r = 0; r < 4; ++r) {
        int row = row0 + wm * 64 + m * 16 + l16 * 4 + r;  // verified C layout (m89/m91)
        float val = acc[m][n][r] + bs;
        if (MODE == 0) {
          int which = col >> 11;            // 0=q 1=k 2=v (uniform per block)
          int rem = col & 2047;
          int h = rem >> 7, dh = rem & 127;
          int b = row >> 11, t = row & 2047;
          int bh = b * NHEADS + h;
          if (which == 0)      Qb[((size_t)bh * TSEQ + t) * DHEAD + dh] = f2bf(val);
          else if (which == 1) Kb[((size_t)bh * TSEQ + t) * DHEAD + dh] = f2bf(val);
          else                 VTb[((size_t)bh * DHEAD + dh) * TSEQ + t] = f2bf(val);
        } else {
          outF[(size_t)row * N + col] = val;
        }
      }
    }
  }
}

// ---------------- causal flash attention, barrier-free ----------------
// grid 1024 blocks; bh = bid>>4 (bh-major for L2 K/V reuse), qblk heavy-first.
// 4 independent waves per block, each owns 32 q rows. KVBLK=64.
// K,V fragments read directly from global (L2-resident); only P uses LDS.
__global__ __launch_bounds__(256, 2) void attn_fwd(
    const unsigned short* __restrict__ Qb,
    const unsigned short* __restrict__ Kb,
    const unsigned short* __restrict__ VTb,
    unsigned short* __restrict__ ctx)
{
  __shared__ unsigned short Psm[4][32 * 72];   // per-wave P[32 q][64 kv], padded
  int bid = blockIdx.x;
  int bh = bid >> 4;
  int qblk = 15 - (bid & 15);     // heavy tiles dispatched first within each bh
  int tid = threadIdx.x, wid = tid >> 6, lane = tid & 63;
  int l15 = lane & 15, l16 = lane >> 4;
  int qbase = qblk * 128 + wid * 32;
  const float scale = 0.08838834764831845f;  // 1/sqrt(128)

  const unsigned short* Kh = Kb + (size_t)bh * TSEQ * DHEAD;   // [t][d]
  const unsigned short* Vh = VTb + (size_t)bh * DHEAD * TSEQ;  // [d][t]
  unsigned short* P = &Psm[wid][0];

  // Q fragments: rows qbase + m*16 + l15, d cols kk*32 + l16*8
  bf16x8 qf[2][4];
  #pragma unroll
  for (int m = 0; m < 2; ++m)
    #pragma unroll
    for (int kk = 0; kk < 4; ++kk)
      qf[m][kk] = *(const bf16x8*)&Qb[((size_t)bh * TSEQ + qbase + m * 16 + l15) * DHEAD
                                      + kk * 32 + l16 * 8];

  f32x4 accO[2][8] = {};
  float mrow[2][4], lrow[2][4];
  #pragma unroll
  for (int m = 0; m < 2; ++m)
    #pragma unroll
    for (int r = 0; r < 4; ++r) { mrow[m][r] = -1e30f; lrow[m][r] = 0.f; }

  // tiles needed by THIS wave (rows up to qbase+31)
  int nt = qblk * 2 + 1 + (wid >> 1);
  for (int jt = 0; jt < nt; ++jt) {
    int kv0 = jt * 64;

    // ---- QK^T: S[32 q][64 kv] ----
    f32x4 S[2][4] = {};
    #pragma unroll
    for (int n = 0; n < 4; ++n) {
      bf16x8 kf[4];
      #pragma unroll
      for (int kk = 0; kk < 4; ++kk)
        kf[kk] = *(const bf16x8*)&Kh[(size_t)(kv0 + n * 16 + l15) * DHEAD + kk * 32 + l16 * 8];
      #pragma unroll
      for (int m = 0; m < 2; ++m)
        #pragma unroll
        for (int kk = 0; kk < 4; ++kk)
          S[m][n] = __builtin_amdgcn_mfma_f32_16x16x32_bf16(qf[m][kk], kf[kk], S[m][n], 0, 0, 0);
    }

    // ---- online softmax (16-lane groups share a q row) ----
    #pragma unroll
    for (int m = 0; m < 2; ++m) {
      #pragma unroll
      for (int r = 0; r < 4; ++r) {
        int qg = qbase + m * 16 + l16 * 4 + r;
        float s0 = S[m][0][r] * scale, s1 = S[m][1][r] * scale;
        float s2 = S[m][2][r] * scale, s3 = S[m][3][r] * scale;
        if (kv0 + l15      > qg) s0 = -1e30f;
        if (kv0 + 16 + l15 > qg) s1 = -1e30f;
        if (kv0 + 32 + l15 > qg) s2 = -1e30f;
        if (kv0 + 48 + l15 > qg) s3 = -1e30f;
        float vmax = fmaxf(fmaxf(s0, s1), fmaxf(s2, s3));
        #pragma unroll
        for (int off = 1; off < 16; off <<= 1) vmax = fmaxf(vmax, __shfl_xor(vmax, off));
        float mnew = fmaxf(mrow[m][r], vmax);
        float alpha = __expf(mrow[m][r] - mnew);
        mrow[m][r] = mnew;
        float p0 = __expf(s0 - mnew), p1 = __expf(s1 - mnew);
        float p2 = __expf(s2 - mnew), p3 = __expf(s3 - mnew);
        float ps = (p0 + p1) + (p2 + p3);
        #pragma unroll
        for (int off = 1; off < 16; off <<= 1) ps += __shfl_xor(ps, off);
        lrow[m][r] = lrow[m][r] * alpha + ps;
        #pragma unroll
        for (int n = 0; n < 8; ++n) accO[m][n][r] *= alpha;
        int qr = m * 16 + l16 * 4 + r;
        P[qr * 72      + l15] = f2bf(p0);
        P[qr * 72 + 16 + l15] = f2bf(p1);
        P[qr * 72 + 32 + l15] = f2bf(p2);
        P[qr * 72 + 48 + l15] = f2bf(p3);
      }
    }

    // ---- PV: accO += P @ V ----
    bf16x8 pf[2][2];
    #pragma unroll
    for (int m = 0; m < 2; ++m)
      #pragma unroll
      for (int kk = 0; kk < 2; ++kk)
        pf[m][kk] = *(const bf16x8*)&P[(m * 16 + l15) * 72 + kk * 32 + l16 * 8];
    #pragma unroll
    for (int n = 0; n < 8; ++n) {
      bf16x8 vf[2];
      #pragma unroll
      for (int kk = 0; kk < 2; ++kk)
        vf[kk] = *(const bf16x8*)&Vh[(size_t)(n * 16 + l15) * TSEQ + kv0 + kk * 32 + l16 * 8];
      #pragma unroll
      for (int m = 0; m < 2; ++m)
        #pragma unroll
        for (int kk = 0; kk < 2; ++kk)
          accO[m][n] = __builtin_amdgcn_mfma_f32_16x16x32_bf16(pf[m][kk], vf[kk], accO[m][n], 0, 0, 0);
    }
  }

  int b = bh >> 4, h = bh & 15;
  #pragma unroll
  for (int m = 0; m < 2; ++m) {
    #pragma unroll
    for (int r = 0; r < 4; ++r) {
      float inv = 1.0f / lrow[m][r];
      int t = qbase + m * 16 + l16 * 4 + r;
      size_t base = ((size_t)b * TSEQ + t) * D_MODEL + h * DHEAD;
      #pragma unroll
      for (int n = 0; n < 8; ++n)
        ctx[base + n * 16 + l15] = f2bf(accO[m][n][r] * inv);
    }
  }
}

extern "C" void kernel_launch(void* const* d_in, const int* in_sizes, int n_in,
                              void* d_out, int out_size, void* d_ws, size_t ws_size,
                              hipStream_t stream)
{
  const float* x     = (const float*)d_in[0];
  const float* w_qkv = (const float*)d_in[1];
  const float* b_qkv = (const float*)d_in[2];
  const float* w_out = (const float*)d_in[3];
  const float* b_out = (const float*)d_in[4];
  float* out = (float*)d_out;

  unsigned short* xb    = (unsigned short*)d_ws;               // [8192][2048]; reused as ctx
  unsigned short* wqkvT = xb    + (size_t)MROWS * D_MODEL;     // [6144][2048]
  unsigned short* woutT = wqkvT + (size_t)NQKV * D_MODEL;      // [2048][2048]
  unsigned short* Qb    = woutT + (size_t)D_MODEL * D_MODEL;   // [64][2048][128]
  unsigned short* Kb    = Qb    + (size_t)BH * TSEQ * DHEAD;
  unsigned short* VTb   = Kb    + (size_t)BH * TSEQ * DHEAD;   // [64][128][2048]
  float2* tab = (float2*)(VTb + (size_t)BH * TSEQ * DHEAD);    // [2048][64]

  cvt_bf16<<<MROWS * D_MODEL / 2048, 256, 0, stream>>>(x, xb, MROWS * D_MODEL);
  transw<<<dim3(NQKV / 32, D_MODEL / 32), 256, 0, stream>>>(w_qkv, wqkvT, D_MODEL, NQKV);
  transw<<<dim3(D_MODEL / 32, D_MODEL / 32), 256, 0, stream>>>(w_out, woutT, D_MODEL, D_MODEL);
  rope_table<<<TSEQ, 64, 0, stream>>>(tab);
  gemm_bt<0><<<dim3(NQKV / 128, MROWS / 128), 256, 0, stream>>>(
      xb, wqkvT, b_qkv, MROWS, NQKV, D_MODEL, Qb, Kb, VTb, nullptr);
  rope_apply<<<BH * TSEQ / 4, 256, 0, stream>>>(Qb, tab);
  rope_apply<<<BH * TSEQ / 4, 256, 0, stream>>>(Kb, tab);
  attn_fwd<<<dim3(16 * BH), 256, 0, stream>>>(Qb, Kb, VTb, xb);
  gemm_bt<1><<<dim3(D_MODEL / 128, MROWS / 128), 256, 0, stream>>>(
      xb, woutT, b_out, MROWS, D_MODEL, D_MODEL, nullptr, nullptr, nullptr, out);
}

// Round 3
// 634.305 us; speedup vs baseline: 1.4256x; 1.4256x over previous
//
#include <hip/hip_runtime.h>

#define D_MODEL 2048
#define NHEADS 16
#define DHEAD 128
#define TSEQ 2048
#define BATCH 4
#define MROWS (BATCH*TSEQ)   // 8192
#define NQKV (3*D_MODEL)     // 6144
#define BH (BATCH*NHEADS)    // 64

typedef __attribute__((ext_vector_type(4))) float f32x4;
typedef __attribute__((ext_vector_type(8))) __bf16 bf16x8;
typedef __attribute__((ext_vector_type(4))) unsigned int u32x4;

__device__ inline unsigned short f2bf(float f) {
  union { float f; unsigned u; } v; v.f = f;
  unsigned r = (v.u + 0x7fffu + ((v.u >> 16) & 1u)) >> 16;
  return (unsigned short)r;
}
__device__ inline float bf2f(unsigned short h) {
  union { unsigned u; float f; } v; v.u = ((unsigned)h) << 16; return v.f;
}

// async global->LDS, 16B per lane (dest = wave-uniform base + lane*16)
__device__ inline void gl_lds16(const unsigned short* g, unsigned short* l) {
  __builtin_amdgcn_global_load_lds(
      (const __attribute__((address_space(1))) unsigned int*)g,
      (__attribute__((address_space(3))) unsigned int*)l, 16, 0, 0);
}

// ---------------- fp32 -> bf16 convert (vectorized, G13) ----------------
__global__ __launch_bounds__(256) void cvt_bf16(const float* __restrict__ in,
                                                unsigned short* __restrict__ out, int n) {
  int i = (blockIdx.x * 256 + threadIdx.x) * 8;
  if (i >= n) return;
  float4 a = *(const float4*)(in + i);
  float4 b = *(const float4*)(in + i + 4);
  union { unsigned short s[8]; u32x4 v; } r;
  r.s[0] = f2bf(a.x); r.s[1] = f2bf(a.y); r.s[2] = f2bf(a.z); r.s[3] = f2bf(a.w);
  r.s[4] = f2bf(b.x); r.s[5] = f2bf(b.y); r.s[6] = f2bf(b.z); r.s[7] = f2bf(b.w);
  *(u32x4*)(out + i) = r.v;
}

// ---------------- w [K][N] fp32 -> wT [N][K] bf16 ----------------
__global__ __launch_bounds__(256) void transw(const float* __restrict__ w,
                                              unsigned short* __restrict__ wt, int K, int N) {
  __shared__ float tile[32][33];
  int n0 = blockIdx.x * 32, k0 = blockIdx.y * 32;
  int x = threadIdx.x & 31, y = threadIdx.x >> 5;
  #pragma unroll
  for (int j = 0; j < 4; ++j)
    tile[y + j * 8][x] = w[(size_t)(k0 + y + j * 8) * N + n0 + x];
  __syncthreads();
  #pragma unroll
  for (int j = 0; j < 4; ++j)
    wt[(size_t)(n0 + y + j * 8) * K + k0 + x] = f2bf(tile[x][y + j * 8]);
}

// ---------------- RoPE cos/sin table: tab[t][f], f in [0,64) ----------------
__global__ void rope_table(float2* __restrict__ tab) {
  int t = blockIdx.x, f = threadIdx.x;
  float inv = __expf(-0.14391156831212787f * (float)f); // ln(10000)/64
  float ang = (float)t * inv;
  tab[t * 64 + f] = make_float2(cosf(ang), sinf(ang));
}

// -------- rotate-half RoPE in place on [BH][T][128] bf16, optional out-scale --------
__global__ __launch_bounds__(256) void rope_apply(unsigned short* __restrict__ X,
                                                  const float2* __restrict__ tab,
                                                  float osc) {
  int row = blockIdx.x * 4 + (threadIdx.x >> 6);
  int f = threadIdx.x & 63;
  int t = row & (TSEQ - 1);
  unsigned short* p = X + (size_t)row * DHEAD;
  float2 cs = tab[t * 64 + f];
  float x1 = bf2f(p[f]), x2 = bf2f(p[f + 64]);
  p[f]      = f2bf((x1 * cs.x - x2 * cs.y) * osc);
  p[f + 64] = f2bf((x2 * cs.x + x1 * cs.y) * osc);
}

// ---------------- GEMM: C[M][N] = A[M][K] @ Bt[N][K]^T + bias ----------------
template<int MODE>
__global__ __launch_bounds__(256) void gemm_bt(
    const unsigned short* __restrict__ A,
    const unsigned short* __restrict__ Bt,
    const float* __restrict__ bias,
    int M, int N, int K,
    unsigned short* __restrict__ Qb,
    unsigned short* __restrict__ Kb,
    unsigned short* __restrict__ VTb,
    float* __restrict__ outF)
{
  __shared__ unsigned short Asm_[128 * 72];
  __shared__ unsigned short Bsm_[128 * 72];
  int tid = threadIdx.x;
  int wid = tid >> 6, lane = tid & 63;
  int wm = wid >> 1, wn = wid & 1;
  int l15 = lane & 15, l16 = lane >> 4;
  int row0 = blockIdx.y * 128, col0 = blockIdx.x * 128;
  f32x4 acc[4][4] = {};

  for (int k0 = 0; k0 < K; k0 += 64) {
    #pragma unroll
    for (int c = 0; c < 4; ++c) {
      int e = (c * 256 + tid) * 8;
      int r = e >> 6, cc = e & 63;
      *(u32x4*)&Asm_[r * 72 + cc] = *(const u32x4*)&A[(size_t)(row0 + r) * K + k0 + cc];
      *(u32x4*)&Bsm_[r * 72 + cc] = *(const u32x4*)&Bt[(size_t)(col0 + r) * K + k0 + cc];
    }
    __syncthreads();
    #pragma unroll
    for (int kk = 0; kk < 2; ++kk) {
      bf16x8 av[4], bv[4];
      #pragma unroll
      for (int m = 0; m < 4; ++m)
        av[m] = *(const bf16x8*)&Asm_[(wm * 64 + m * 16 + l15) * 72 + kk * 32 + l16 * 8];
      #pragma unroll
      for (int n = 0; n < 4; ++n)
        bv[n] = *(const bf16x8*)&Bsm_[(wn * 64 + n * 16 + l15) * 72 + kk * 32 + l16 * 8];
      #pragma unroll
      for (int m = 0; m < 4; ++m)
        #pragma unroll
        for (int n = 0; n < 4; ++n)
          acc[m][n] = __builtin_amdgcn_mfma_f32_16x16x32_bf16(av[m], bv[n], acc[m][n], 0, 0, 0);
    }
    __syncthreads();
  }

  #pragma unroll
  for (int m = 0; m < 4; ++m) {
    #pragma unroll
    for (int n = 0; n < 4; ++n) {
      int col = col0 + wn * 64 + n * 16 + l15;
      float bs = bias[col];
      #pragma unroll
      for (int r = 0; r < 4; ++r) {
        int row = row0 + wm * 64 + m * 16 + l16 * 4 + r;  // verified C layout (m89/m91)
        float val = acc[m][n][r] + bs;
        if (MODE == 0) {
          int which = col >> 11;
          int rem = col & 2047;
          int h = rem >> 7, dh = rem & 127;
          int b = row >> 11, t = row & 2047;
          int bh = b * NHEADS + h;
          if (which == 0)      Qb[((size_t)bh * TSEQ + t) * DHEAD + dh] = f2bf(val);
          else if (which == 1) Kb[((size_t)bh * TSEQ + t) * DHEAD + dh] = f2bf(val);
          else                 VTb[((size_t)bh * DHEAD + dh) * TSEQ + t] = f2bf(val);
        } else {
          outF[(size_t)row * N + col] = val;
        }
      }
    }
  }
}

// ---------------- causal flash attention: paired q-tiles, LDS dbuf K/V ----------------
// grid 512: bh = bid&63, pair p = bid>>6; q-tiles (15-p) then (p), 128 rows each.
// 4 waves x 32 q rows. KVBLK=64. K/V staged via global_load_lds with pre-swizzled
// source (T2 both-sides XOR, rule #21); one barrier per kv tile (T3 minimal 2-phase).
// Q pre-scaled by scale*log2e at RoPE -> softmax in exp2 domain.
__global__ __launch_bounds__(256, 2) void attn_fwd(
    const unsigned short* __restrict__ Qb,
    const unsigned short* __restrict__ Kb,
    const unsigned short* __restrict__ VTb,
    unsigned short* __restrict__ ctx)
{
  __shared__ unsigned short Ksm[2][64 * 128];   // [kv][d], 256B rows, 16KB/buf
  __shared__ unsigned short Vsm[2][128 * 64];   // [d][kv], 128B rows, 16KB/buf
  __shared__ unsigned short Psm[4][32 * 64];    // per-wave P, 128B rows, swizzled
  int bid = blockIdx.x;
  int bh = bid & 63, pr = bid >> 6;
  int hi = 15 - pr, lo = pr;
  int tid = threadIdx.x, wid = tid >> 6, lane = tid & 63;
  int l15 = lane & 15, l16 = lane >> 4;
  const unsigned short* Kh = Kb + (size_t)bh * TSEQ * DHEAD;
  const unsigned short* Vh = VTb + (size_t)bh * DHEAD * TSEQ;
  unsigned short* P = &Psm[wid][0];
  int swzl = (l15 & 7) << 4;

  // staging precompute (source pre-swizzled so linear LDS + XOR read match)
  int krow = tid >> 4;
  int kcol = (((tid & 15) << 4) ^ ((krow & 7) << 4)) >> 1;   // elems
  int vrow = tid >> 3;
  int vcol = (((tid & 7) << 4) ^ ((vrow & 7) << 4)) >> 1;    // elems
  int ldsl = tid * 8;                                        // elems, +2048/pass

  // fragment read column offsets (elems, swizzled)
  int ck[4];
  #pragma unroll
  for (int kk = 0; kk < 4; ++kk) ck[kk] = ((kk * 64 + l16 * 16) ^ swzl) >> 1;

  bf16x8 qf[2][4];
  f32x4 accO[2][8];
  float mrow[2][4], lrow[2][4];

  int qbase = hi * 128 + wid * 32;
  #pragma unroll
  for (int m = 0; m < 2; ++m) {
    #pragma unroll
    for (int n = 0; n < 8; ++n) accO[m][n] = (f32x4)0.f;
    #pragma unroll
    for (int r = 0; r < 4; ++r) { mrow[m][r] = -1e30f; lrow[m][r] = 0.f; }
    #pragma unroll
    for (int kk = 0; kk < 4; ++kk)
      qf[m][kk] = *(const bf16x8*)&Qb[((size_t)bh * TSEQ + qbase + m * 16 + l15) * DHEAD
                                      + kk * 32 + l16 * 8];
  }

  int nt0 = 2 * hi + 2;
  int ntt = nt0 + 2 * lo + 2;

  // prologue: stage tile 0 into buf 0
  {
    const unsigned short* kg = Kh + krow * DHEAD + kcol;
    const unsigned short* vg = Vh + (size_t)vrow * TSEQ + vcol;
    #pragma unroll
    for (int ps = 0; ps < 4; ++ps) {
      gl_lds16(kg + ps * 16 * DHEAD, &Ksm[0][ldsl + ps * 2048]);
      gl_lds16(vg + (size_t)ps * 32 * TSEQ, &Vsm[0][ldsl + ps * 2048]);
    }
  }
  __syncthreads();

  for (int it = 0; it < ntt; ++it) {
    int buf = it & 1;
    int kv0 = ((it >= nt0) ? (it - nt0) : it) * 64;

    // prefetch next tile into buf^1 (prev barrier guarantees buf^1 free)
    if (it + 1 < ntt) {
      int n2 = it + 1;
      int kv2 = ((n2 >= nt0) ? (n2 - nt0) : n2) * 64;
      const unsigned short* kg = Kh + (size_t)(kv2 + krow) * DHEAD + kcol;
      const unsigned short* vg = Vh + (size_t)vrow * TSEQ + kv2 + vcol;
      #pragma unroll
      for (int ps = 0; ps < 4; ++ps) {
        gl_lds16(kg + ps * 16 * DHEAD, &Ksm[buf ^ 1][ldsl + ps * 2048]);
        gl_lds16(vg + (size_t)ps * 32 * TSEQ, &Vsm[buf ^ 1][ldsl + ps * 2048]);
      }
    }

    if (kv0 <= qbase + 31) {      // wave-uniform causal activity test
      const unsigned short* Kt = Ksm[buf];
      const unsigned short* Vt = Vsm[buf];

      // ---- QK^T ----
      f32x4 S[2][4] = {};
      #pragma unroll
      for (int n = 0; n < 4; ++n) {
        bf16x8 kf[4];
        #pragma unroll
        for (int kk = 0; kk < 4; ++kk)
          kf[kk] = *(const bf16x8*)&Kt[(n * 16 + l15) * DHEAD + ck[kk]];
        #pragma unroll
        for (int m = 0; m < 2; ++m)
          #pragma unroll
          for (int kk = 0; kk < 4; ++kk)
            S[m][n] = __builtin_amdgcn_mfma_f32_16x16x32_bf16(qf[m][kk], kf[kk], S[m][n], 0, 0, 0);
      }

      // ---- online softmax (exp2 domain; Q carries scale*log2e) ----
      #pragma unroll
      for (int m = 0; m < 2; ++m) {
        #pragma unroll
        for (int r = 0; r < 4; ++r) {
          int qg = qbase + m * 16 + l16 * 4 + r;
          float s0 = S[m][0][r], s1 = S[m][1][r], s2 = S[m][2][r], s3 = S[m][3][r];
          if (kv0 + l15      > qg) s0 = -1e30f;
          if (kv0 + 16 + l15 > qg) s1 = -1e30f;
          if (kv0 + 32 + l15 > qg) s2 = -1e30f;
          if (kv0 + 48 + l15 > qg) s3 = -1e30f;
          float vmax = fmaxf(fmaxf(s0, s1), fmaxf(s2, s3));
          #pragma unroll
          for (int off = 1; off < 16; off <<= 1) vmax = fmaxf(vmax, __shfl_xor(vmax, off));
          float mnew = fmaxf(mrow[m][r], vmax);
          float alpha = exp2f(mrow[m][r] - mnew);
          mrow[m][r] = mnew;
          float p0 = exp2f(s0 - mnew), p1 = exp2f(s1 - mnew);
          float p2 = exp2f(s2 - mnew), p3 = exp2f(s3 - mnew);
          float ps = (p0 + p1) + (p2 + p3);
          #pragma unroll
          for (int off = 1; off < 16; off <<= 1) ps += __shfl_xor(ps, off);
          lrow[m][r] = lrow[m][r] * alpha + ps;
          #pragma unroll
          for (int n = 0; n < 8; ++n) accO[m][n][r] *= alpha;
          int qr = m * 16 + l16 * 4 + r;
          int ws = (qr & 7) << 4;
          P[qr * 64 + ((((l15 << 1))      ^ ws) >> 1)] = f2bf(p0);
          P[qr * 64 + (((32 + (l15 << 1)) ^ ws) >> 1)] = f2bf(p1);
          P[qr * 64 + (((64 + (l15 << 1)) ^ ws) >> 1)] = f2bf(p2);
          P[qr * 64 + (((96 + (l15 << 1)) ^ ws) >> 1)] = f2bf(p3);
        }
      }

      // ---- PV ----
      bf16x8 pf[2][2];
      #pragma unroll
      for (int m = 0; m < 2; ++m)
        #pragma unroll
        for (int kk = 0; kk < 2; ++kk)
          pf[m][kk] = *(const bf16x8*)&P[(m * 16 + l15) * 64 + ck[kk]];
      #pragma unroll
      for (int n = 0; n < 8; ++n) {
        bf16x8 vf[2];
        #pragma unroll
        for (int kk = 0; kk < 2; ++kk)
          vf[kk] = *(const bf16x8*)&Vt[(n * 16 + l15) * 64 + ck[kk]];
        #pragma unroll
        for (int m = 0; m < 2; ++m)
          #pragma unroll
          for (int kk = 0; kk < 2; ++kk)
            accO[m][n] = __builtin_amdgcn_mfma_f32_16x16x32_bf16(pf[m][kk], vf[kk], accO[m][n], 0, 0, 0);
      }
    }

    // segment boundary: flush heavy tile, reinit for light tile
    if (it == nt0 - 1) {
      int b = bh >> 4, h = bh & 15;
      #pragma unroll
      for (int m = 0; m < 2; ++m)
        #pragma unroll
        for (int r = 0; r < 4; ++r) {
          float inv = 1.0f / lrow[m][r];
          int t = qbase + m * 16 + l16 * 4 + r;
          size_t base = ((size_t)b * TSEQ + t) * D_MODEL + h * DHEAD;
          #pragma unroll
          for (int n = 0; n < 8; ++n)
            ctx[base + n * 16 + l15] = f2bf(accO[m][n][r] * inv);
        }
      qbase = lo * 128 + wid * 32;
      #pragma unroll
      for (int m = 0; m < 2; ++m) {
        #pragma unroll
        for (int n = 0; n < 8; ++n) accO[m][n] = (f32x4)0.f;
        #pragma unroll
        for (int r = 0; r < 4; ++r) { mrow[m][r] = -1e30f; lrow[m][r] = 0.f; }
        #pragma unroll
        for (int kk = 0; kk < 4; ++kk)
          qf[m][kk] = *(const bf16x8*)&Qb[((size_t)bh * TSEQ + qbase + m * 16 + l15) * DHEAD
                                          + kk * 32 + l16 * 8];
      }
    }

    __syncthreads();   // drains our staged loads (vmcnt) + releases buffers
  }

  // flush light tile
  {
    int b = bh >> 4, h = bh & 15;
    #pragma unroll
    for (int m = 0; m < 2; ++m)
      #pragma unroll
      for (int r = 0; r < 4; ++r) {
        float inv = 1.0f / lrow[m][r];
        int t = qbase + m * 16 + l16 * 4 + r;
        size_t base = ((size_t)b * TSEQ + t) * D_MODEL + h * DHEAD;
        #pragma unroll
        for (int n = 0; n < 8; ++n)
          ctx[base + n * 16 + l15] = f2bf(accO[m][n][r] * inv);
      }
  }
}

extern "C" void kernel_launch(void* const* d_in, const int* in_sizes, int n_in,
                              void* d_out, int out_size, void* d_ws, size_t ws_size,
                              hipStream_t stream)
{
  const float* x     = (const float*)d_in[0];
  const float* w_qkv = (const float*)d_in[1];
  const float* b_qkv = (const float*)d_in[2];
  const float* w_out = (const float*)d_in[3];
  const float* b_out = (const float*)d_in[4];
  float* out = (float*)d_out;

  unsigned short* xb    = (unsigned short*)d_ws;               // [8192][2048]; reused as ctx
  unsigned short* wqkvT = xb    + (size_t)MROWS * D_MODEL;     // [6144][2048]
  unsigned short* woutT = wqkvT + (size_t)NQKV * D_MODEL;      // [2048][2048]
  unsigned short* Qb    = woutT + (size_t)D_MODEL * D_MODEL;   // [64][2048][128]
  unsigned short* Kb    = Qb    + (size_t)BH * TSEQ * DHEAD;
  unsigned short* VTb   = Kb    + (size_t)BH * TSEQ * DHEAD;   // [64][128][2048]
  float2* tab = (float2*)(VTb + (size_t)BH * TSEQ * DHEAD);    // [2048][64]

  const float SCALE_Q = 0.08838834764831845f * 1.4426950408889634f; // 1/sqrt(128) * log2(e)

  cvt_bf16<<<MROWS * D_MODEL / 2048, 256, 0, stream>>>(x, xb, MROWS * D_MODEL);
  transw<<<dim3(NQKV / 32, D_MODEL / 32), 256, 0, stream>>>(w_qkv, wqkvT, D_MODEL, NQKV);
  transw<<<dim3(D_MODEL / 32, D_MODEL / 32), 256, 0, stream>>>(w_out, woutT, D_MODEL, D_MODEL);
  rope_table<<<TSEQ, 64, 0, stream>>>(tab);
  gemm_bt<0><<<dim3(NQKV / 128, MROWS / 128), 256, 0, stream>>>(
      xb, wqkvT, b_qkv, MROWS, NQKV, D_MODEL, Qb, Kb, VTb, nullptr);
  rope_apply<<<BH * TSEQ / 4, 256, 0, stream>>>(Qb, tab, SCALE_Q);
  rope_apply<<<BH * TSEQ / 4, 256, 0, stream>>>(Kb, tab, 1.0f);
  attn_fwd<<<dim3(512), 256, 0, stream>>>(Qb, Kb, VTb, xb);
  gemm_bt<1><<<dim3(D_MODEL / 128, MROWS / 128), 256, 0, stream>>>(
      xb, woutT, b_out, MROWS, D_MODEL, D_MODEL, nullptr, nullptr, nullptr, out);
}